// Round 1
// baseline (216.497 us; speedup 1.0000x reference)
//
#include <hip/hip_runtime.h>

// Problem constants (fixed by setup_inputs: 4096x4096 fp32).
#define H 4096
#define W 4096
#define TILE 64
#define PADR 7                    // max k = 15 -> radius 7
#define PT (TILE + 2 * PADR)      // 78 padded tile extent
#define PROWS (PT + 1)            // 79 (row/col 0 are zeros of the prefix sum)
#define STRIDE 81                 // odd stride: row-scan lanes hit all 32 banks (2/bank = free)

__global__ __launch_bounds__(256) void multi_box_kernel(
    const float* __restrict__ x,
    const float* __restrict__ base,
    float* __restrict__ out)
{
    __shared__ float P[PROWS * STRIDE];  // 79*81*4 = 25596 B -> ~6 blocks/CU by LDS

    const int tid = threadIdx.x;
    const int bx0 = blockIdx.x * TILE;
    const int by0 = blockIdx.y * TILE;

    // ---- Load padded tile into P[1..78][1..78]; clamp == replicate padding ----
    for (int idx = tid; idx < PT * PT; idx += 256) {
        int i = idx / PT;
        int j = idx - i * PT;
        int gy = by0 + i - PADR; gy = min(max(gy, 0), H - 1);
        int gx = bx0 + j - PADR; gx = min(max(gx, 0), W - 1);
        P[(i + 1) * STRIDE + (j + 1)] = x[gy * W + gx];
    }
    // zero border (row 0 and column 0 of the prefix array)
    if (tid < PROWS) {
        P[tid] = 0.0f;            // row 0
        P[tid * STRIDE] = 0.0f;   // col 0
    }
    __syncthreads();

    // ---- Row prefix: thread t scans row t+1 ----
    if (tid < PT) {
        float v = 0.0f;
        int b = (tid + 1) * STRIDE;
        for (int j = 1; j <= PT; ++j) {
            v += P[b + j];
            P[b + j] = v;
        }
    }
    __syncthreads();

    // ---- Column prefix: thread t scans column t+1 (consecutive lanes -> conflict-free) ----
    if (tid < PT) {
        float v = 0.0f;
        int c = tid + 1;
        for (int i = 1; i <= PT; ++i) {
            v += P[i * STRIDE + c];
            P[i * STRIDE + c] = v;
        }
    }
    __syncthreads();

    // ---- Epilogue: lane owns one column (conflict-free & coalesced), 16 rows ----
    // P[i][j] = sum over padded tile [0..i-1][0..j-1].
    // Output pixel (y,x): window rows [y+7-r, y+8+r), cols [x+7-r, x+8+r).
    const int lx = tid & 63;           // column within tile
    const int y0 = (tid >> 6) * 16;    // first of 16 rows
    const int gx = bx0 + lx;

    int vbase = y0 * STRIDE + lx;      // minimal-corner base -> all offsets positive immediates
    #pragma unroll
    for (int yy = 0; yy < 16; ++yy) {
        const int y = y0 + yy;
        float acc = 0.0f;
        #pragma unroll
        for (int r = 1; r <= 7; ++r) {
            // offsets relative to vbase = y*81 + x, all compile-time constants:
            // A1=y+8+r, A0=y+7-r, B1=x+8+r, B0=x+7-r
            const int o11 = (8 + r) * STRIDE + (8 + r);  // P[A1][B1]
            const int o10 = (8 + r) * STRIDE + (7 - r);  // P[A1][B0]
            const int o01 = (7 - r) * STRIDE + (8 + r);  // P[A0][B1]
            const int o00 = (7 - r) * STRIDE + (7 - r);  // P[A0][B0]
            float s = (P[vbase + o11] - P[vbase + o10]) - (P[vbase + o01] - P[vbase + o00]);
            const int k = 2 * r + 1;
            const float wk = 1.0f / (7.0f * (float)(k * k));
            acc = fmaf(s, wk, acc);
        }
        const int g = (by0 + y) * W + gx;
        out[g] = acc * base[g];
        vbase += STRIDE;
    }
}

extern "C" void kernel_launch(void* const* d_in, const int* in_sizes, int n_in,
                              void* d_out, int out_size, void* d_ws, size_t ws_size,
                              hipStream_t stream) {
    const float* x    = (const float*)d_in[0];
    const float* base = (const float*)d_in[1];
    float* out        = (float*)d_out;

    dim3 grid(W / TILE, H / TILE);  // 64 x 64 tiles
    multi_box_kernel<<<grid, 256, 0, stream>>>(x, base, out);
}

// Round 2
// 191.038 us; speedup vs baseline: 1.1333x; 1.1333x over previous
//
#include <hip/hip_runtime.h>

// Problem constants (fixed by setup_inputs: 4096x4096 fp32).
#define H 4096
#define W 4096
#define TILE 64
#define PADR 7                    // max k = 15 -> radius 7
#define PT (TILE + 2 * PADR)      // 78 padded tile extent
#define PROWS (PT + 1)            // 79 (row/col 0 are zeros of the prefix sum)
#define STRIDE 81                 // odd stride: scan lanes spread over all 32 banks

__global__ __launch_bounds__(256) void multi_box_kernel(
    const float* __restrict__ x,
    const float* __restrict__ base,
    float* __restrict__ out)
{
    __shared__ float P[PROWS * STRIDE];  // 25.6 KB -> 6 blocks/CU by LDS

    const int tid = threadIdx.x;
    const int bx0 = blockIdx.x * TILE;
    const int by0 = blockIdx.y * TILE;

    // ---- Load padded tile into P[1..78][1..78]; clamp == replicate padding ----
    for (int idx = tid; idx < PT * PT; idx += 256) {
        int i = idx / PT;
        int j = idx - i * PT;
        int gy = min(max(by0 + i - PADR, 0), H - 1);
        int gx = min(max(bx0 + j - PADR, 0), W - 1);
        P[(i + 1) * STRIDE + (j + 1)] = x[gy * W + gx];
    }
    if (tid < PROWS) {
        P[tid] = 0.0f;            // guard row 0
        P[tid * STRIDE] = 0.0f;   // guard col 0
    }
    __syncthreads();

    // ---- Row prefix: thread t scans row t+1. Fully unrolled: offsets 0..77
    // dwords from runtime base -> compiler merges into ds_read2/write2_b32.
    if (tid < PT) {
        float v = 0.0f;
        const int rb = (tid + 1) * STRIDE + 1;
        #pragma unroll
        for (int j = 0; j < PT; ++j) {
            v += P[rb + j];
            P[rb + j] = v;
        }
    }
    __syncthreads();

    // ---- Column prefix: thread t scans column t+1. Groups of 4 rows with a
    // moving base: in-group dword offsets {0,81,162,243} <= 255 -> read2/write2.
    if (tid < PT) {
        float v = 0.0f;
        int cb = STRIDE + (tid + 1);
        #pragma unroll 1
        for (int g = 0; g < PT / 4; ++g) {   // 19 groups of 4
            float a0 = P[cb];
            float a1 = P[cb + STRIDE];
            float a2 = P[cb + 2 * STRIDE];
            float a3 = P[cb + 3 * STRIDE];
            float v0 = v + a0;
            float v1 = v0 + a1;
            float v2 = v1 + a2;
            float v3 = v2 + a3;
            P[cb] = v0;
            P[cb + STRIDE] = v1;
            P[cb + 2 * STRIDE] = v2;
            P[cb + 3 * STRIDE] = v3;
            v = v3;
            cb += 4 * STRIDE;
        }
        // tail: 78 = 4*19 + 2
        float t0 = v + P[cb];            P[cb] = t0;
        float t1 = t0 + P[cb + STRIDE]; P[cb + STRIDE] = t1;
    }
    __syncthreads();

    // ---- Epilogue: lane owns one column, 16 rows. 28 corner reads per pixel,
    // grouped under 4 opaque bases so every pair (B1,B0) of the same row merges
    // into one ds_read2_b32 (both offsets <= 255 dwords from its base).
    const int lx = tid & 63;
    const int y0 = (tid >> 6) * 16;
    const int gx = bx0 + lx;

    int vb = y0 * STRIDE + lx;
    #pragma unroll
    for (int yy = 0; yy < 16; ++yy) {
        int ia = vb;                        // A0 rows +0..+2   (r = 7,6,5)
        int ib = vb + 3 * STRIDE;           // A0 rows +3..+6   (r = 4,3,2,1)
        int ic = vb + 9 * STRIDE;           // A1 rows +9..+11  (r = 1,2,3)
        int id = vb + 12 * STRIDE + 3;      // A1 rows +12..+15 (r = 4..7), +3 keeps offsets <= 255
        asm volatile("" : "+v"(ia), "+v"(ib), "+v"(ic), "+v"(id));

        float acc = 0.0f;
        #pragma unroll
        for (int r = 1; r <= 7; ++r) {
            const int c0 = 7 - r, c1 = 8 + r;
            float a0b0, a0b1, a1b0, a1b1;
            if (r >= 5) {   // A0 row offset (7-r) in 0..2 from ia
                a0b0 = P[ia + (7 - r) * STRIDE + c0];
                a0b1 = P[ia + (7 - r) * STRIDE + c1];
            } else {        // A0 row offset (7-r) in 3..6 -> (4-r) from ib
                a0b0 = P[ib + (4 - r) * STRIDE + c0];
                a0b1 = P[ib + (4 - r) * STRIDE + c1];
            }
            if (r <= 3) {   // A1 row offset (8+r) in 9..11 -> (r-1) from ic
                a1b0 = P[ic + (r - 1) * STRIDE + c0];
                a1b1 = P[ic + (r - 1) * STRIDE + c1];
            } else {        // A1 row offset (8+r) in 12..15 -> (r-4) from id (shifted +3)
                a1b0 = P[id + (r - 4) * STRIDE + c0 - 3];
                a1b1 = P[id + (r - 4) * STRIDE + c1 - 3];
            }
            const int k = 2 * r + 1;
            const float wk = 1.0f / (7.0f * (float)(k * k));
            acc = fmaf((a1b1 - a1b0) - (a0b1 - a0b0), wk, acc);
        }
        const int g = (by0 + y0 + yy) * W + gx;
        out[g] = acc * base[g];
        vb += STRIDE;
    }
}

extern "C" void kernel_launch(void* const* d_in, const int* in_sizes, int n_in,
                              void* d_out, int out_size, void* d_ws, size_t ws_size,
                              hipStream_t stream) {
    const float* x    = (const float*)d_in[0];
    const float* base = (const float*)d_in[1];
    float* out        = (float*)d_out;

    dim3 grid(W / TILE, H / TILE);  // 64 x 64 tiles
    multi_box_kernel<<<grid, 256, 0, stream>>>(x, base, out);
}